// Round 1
// baseline (284.443 us; speedup 1.0000x reference)
//
#include <hip/hip_runtime.h>
#include <hip/hip_bf16.h>

// Problem constants (B=2, T=4096, D=1024, H=512)
#define TB 2
#define TT 4096
#define TD 1024
#define TH 512
#define TM 8192            // B*T tokens
#define EPS 1e-5f

typedef __bf16 bf16;
typedef __bf16 bf16x4 __attribute__((ext_vector_type(4)));
typedef __bf16 bf16x8 __attribute__((ext_vector_type(8)));
typedef float  f32x4  __attribute__((ext_vector_type(4)));

#define GLOBAL_AS __attribute__((address_space(1)))
#define LDS_AS    __attribute__((address_space(3)))

// ---------------------------------------------------------------------------
// Cast x (f32) into XM bf16 [8192][2048], columns 0..1023 (cols 1024.. are msg)
// ---------------------------------------------------------------------------
__global__ __launch_bounds__(256) void cast_x_kernel(const float4* __restrict__ x4,
                                                     bf16* __restrict__ XM) {
    int i = blockIdx.x * 256 + threadIdx.x;      // over 8192*1024/4 float4s
    float4 v = x4[i];
    int row = i >> 8;                            // 256 float4 per 1024-col row
    int c4  = i & 255;
    bf16x4 o;
    o[0] = (bf16)v.x; o[1] = (bf16)v.y; o[2] = (bf16)v.z; o[3] = (bf16)v.w;
    *(bf16x4*)(XM + (size_t)row * 2048 + c4 * 4) = o;
}

// ---------------------------------------------------------------------------
// Transpose f32 [K][N] (row-major, stride N) -> bf16 dst[dstOff+n][k], stride dstStride
// grid = (N/32, K/32), block = 256 (32x8)
// ---------------------------------------------------------------------------
__global__ __launch_bounds__(256) void transpose_to_bf16(const float* __restrict__ src,
                                                         bf16* __restrict__ dst,
                                                         int N, int dstOff, int dstStride) {
    __shared__ float tile[32][33];
    int n0 = blockIdx.x * 32, k0 = blockIdx.y * 32;
    int tx = threadIdx.x & 31, ty = threadIdx.x >> 5;   // 32 x 8
#pragma unroll
    for (int r = 0; r < 32; r += 8)
        tile[ty + r][tx] = src[(size_t)(k0 + ty + r) * N + n0 + tx];
    __syncthreads();
#pragma unroll
    for (int r = 0; r < 32; r += 8)
        dst[(size_t)(dstOff + n0 + ty + r) * dstStride + k0 + tx] = (bf16)tile[tx][ty + r];
}

// ---------------------------------------------------------------------------
// bf16 GEMM (B-transposed): C[M][N] = A[M][K] @ BT[N][K]^T, fp32 out.
// m97 structure: 128x128 tile, BK=32, 4 waves, 64x64/wave, global_load_lds w=16.
// ---------------------------------------------------------------------------
__global__ __launch_bounds__(256) void gemm_bt(const bf16* __restrict__ A, int lda,
                                               const bf16* __restrict__ BT,
                                               float* __restrict__ C, int N, int K) {
    __shared__ bf16 As[128 * 32];
    __shared__ bf16 Bs[128 * 32];
    const int m0 = blockIdx.y * 128;
    const int n0 = blockIdx.x * 128;
    const int tid = threadIdx.x;
    const int wave = tid >> 6, lane = tid & 63;
    const int wr = (wave >> 1) * 64, wc = (wave & 1) * 64;
    const int lrow = lane & 15, lk = (lane >> 4) * 8;

    f32x4 acc[4][4] = {};

    for (int k0 = 0; k0 < K; k0 += 32) {
        __syncthreads();   // previous compute done before overwrite
#pragma unroll
        for (int c = 0; c < 2; ++c) {
            int e = (c * 256 + tid) * 8;         // bf16 element offset in 128x32 tile
            int row = e >> 5, col = e & 31;
            const bf16* ga = A  + (size_t)(m0 + row) * lda + k0 + col;
            const bf16* gb = BT + (size_t)(n0 + row) * K   + k0 + col;
            __builtin_amdgcn_global_load_lds((const GLOBAL_AS void*)ga,
                                             (LDS_AS void*)(As + e), 16, 0, 0);
            __builtin_amdgcn_global_load_lds((const GLOBAL_AS void*)gb,
                                             (LDS_AS void*)(Bs + e), 16, 0, 0);
        }
        __syncthreads();   // drains vmcnt (compiler emits waitcnt before s_barrier)

        bf16x8 af[4], bfr[4];
#pragma unroll
        for (int i = 0; i < 4; ++i) {
            af[i]  = *(const bf16x8*)(As + (wr + i * 16 + lrow) * 32 + lk);
            bfr[i] = *(const bf16x8*)(Bs + (wc + i * 16 + lrow) * 32 + lk);
        }
#pragma unroll
        for (int i = 0; i < 4; ++i)
#pragma unroll
            for (int j = 0; j < 4; ++j)
                acc[i][j] = __builtin_amdgcn_mfma_f32_16x16x32_bf16(af[i], bfr[j], acc[i][j], 0, 0, 0);
    }

    // Epilogue: C/D layout col=lane&15, row=(lane>>4)*4+reg
    const int lr = (lane >> 4) * 4, lc = lane & 15;
#pragma unroll
    for (int i = 0; i < 4; ++i)
#pragma unroll
        for (int j = 0; j < 4; ++j)
#pragma unroll
            for (int r = 0; r < 4; ++r)
                C[(size_t)(m0 + wr + i * 16 + lr + r) * N + (n0 + wc + j * 16 + lc)] = acc[i][j][r];
}

// ---------------------------------------------------------------------------
// tau + msg: per token (block), UVV = [U(512) | Vn(512) | V(1024)] fp32 per row.
// msg[t] = sum_w tau[t,w] * V[t-w-1] (valid) + (sum_w tau) * wv_b
// writes msg as bf16 into XM cols 1024..2047
// ---------------------------------------------------------------------------
__global__ __launch_bounds__(256) void taumsg_kernel(const float* __restrict__ UVV,
                                                     const float* __restrict__ b1,
                                                     const float* __restrict__ b2,
                                                     const float* __restrict__ w2,
                                                     const float* __restrict__ wv_b,
                                                     bf16* __restrict__ XM) {
    const int row = blockIdx.x;          // token 0..8191
    const int t = row & (TT - 1);
    const int tid = threadIdx.x;
    const float* U = UVV + (size_t)row * 2048;

    float partial[4] = {0.f, 0.f, 0.f, 0.f};
    for (int h = tid; h < TH; h += 256) {        // 2 iters
        float u = U[h] + b1[h];
        float w2h = w2[h];
#pragma unroll
        for (int w = 0; w < 4; ++w) {
            float vn = (t - w - 1 >= 0) ? UVV[(size_t)(row - w - 1) * 2048 + 512 + h] : 0.f;
            float z = u + vn;
            float hid = z / (1.f + __expf(-z));  // silu
            partial[w] += hid * w2h;
        }
    }
#pragma unroll
    for (int w = 0; w < 4; ++w)
        for (int off = 32; off; off >>= 1)
            partial[w] += __shfl_down(partial[w], off, 64);

    __shared__ float red[4][4];
    __shared__ float staus[4];
    const int lane = tid & 63, wave = tid >> 6;
    if (lane == 0)
#pragma unroll
        for (int w = 0; w < 4; ++w) red[w][wave] = partial[w];
    __syncthreads();
    if (tid < 4) {
        float s = red[tid][0] + red[tid][1] + red[tid][2] + red[tid][3] + b2[0];
        staus[tid] = 1.f / (1.f + __expf(-s));
    }
    __syncthreads();
    const float tau0 = staus[0], tau1 = staus[1], tau2 = staus[2], tau3 = staus[3];
    const float tsum = tau0 + tau1 + tau2 + tau3;

    for (int d = tid; d < TD; d += 256) {        // 4 iters
        float m = tsum * wv_b[d];
        if (t >= 1) m += tau0 * UVV[(size_t)(row - 1) * 2048 + 1024 + d];
        if (t >= 2) m += tau1 * UVV[(size_t)(row - 2) * 2048 + 1024 + d];
        if (t >= 3) m += tau2 * UVV[(size_t)(row - 3) * 2048 + 1024 + d];
        if (t >= 4) m += tau3 * UVV[(size_t)(row - 4) * 2048 + 1024 + d];
        XM[(size_t)row * 2048 + 1024 + d] = (bf16)m;
    }
}

// ---------------------------------------------------------------------------
// LayerNorm over D=1024: out = (y+merge_b - mu) * rsqrt(var+eps) * gamma + beta
// ---------------------------------------------------------------------------
__global__ __launch_bounds__(256) void ln_kernel(const float* __restrict__ Y,
                                                 const float* __restrict__ merge_b,
                                                 const float* __restrict__ gamma,
                                                 const float* __restrict__ beta,
                                                 float* __restrict__ out) {
    const int row = blockIdx.x;
    const int tid = threadIdx.x;
    const float* y = Y + (size_t)row * TD;
    float v[4];
    float s = 0.f, ss = 0.f;
#pragma unroll
    for (int i = 0; i < 4; ++i) {
        int d = tid + i * 256;
        v[i] = y[d] + merge_b[d];
        s += v[i]; ss += v[i] * v[i];
    }
    for (int off = 32; off; off >>= 1) {
        s  += __shfl_down(s, off, 64);
        ss += __shfl_down(ss, off, 64);
    }
    __shared__ float rs[4], rss[4];
    __shared__ float smu, srstd;
    const int lane = tid & 63, wave = tid >> 6;
    if (lane == 0) { rs[wave] = s; rss[wave] = ss; }
    __syncthreads();
    if (tid == 0) {
        float S = rs[0] + rs[1] + rs[2] + rs[3];
        float SS = rss[0] + rss[1] + rss[2] + rss[3];
        float mu = S * (1.f / TD);
        float var = SS * (1.f / TD) - mu * mu;
        smu = mu; srstd = rsqrtf(var + EPS);
    }
    __syncthreads();
    const float mu = smu, r = srstd;
#pragma unroll
    for (int i = 0; i < 4; ++i) {
        int d = tid + i * 256;
        out[(size_t)row * TD + d] = (v[i] - mu) * r * gamma[d] + beta[d];
    }
}

// ---------------------------------------------------------------------------
extern "C" void kernel_launch(void* const* d_in, const int* in_sizes, int n_in,
                              void* d_out, int out_size, void* d_ws, size_t ws_size,
                              hipStream_t stream) {
    const float* x       = (const float*)d_in[0];
    const float* w1      = (const float*)d_in[1];
    const float* b1      = (const float*)d_in[2];
    const float* w2      = (const float*)d_in[3];
    const float* b2      = (const float*)d_in[4];
    const float* wv_w    = (const float*)d_in[5];
    const float* wv_b    = (const float*)d_in[6];
    const float* merge_w = (const float*)d_in[7];
    const float* merge_b = (const float*)d_in[8];
    const float* gamma   = (const float*)d_in[9];
    const float* beta    = (const float*)d_in[10];
    float* out = (float*)d_out;

    char* ws = (char*)d_ws;
    bf16*  XM     = (bf16*)ws;   ws += (size_t)TM * 2048 * 2;   // [8192][2048] = X | msg
    bf16*  WbigT  = (bf16*)ws;   ws += (size_t)2048 * 1024 * 2; // [2048 n][1024 k]
    bf16*  MergeT = (bf16*)ws;   ws += (size_t)1024 * 2048 * 2; // [1024 n][2048 k]
    float* UVV    = (float*)ws;  ws += (size_t)TM * 2048 * 4;   // [8192][U|Vn|V]
    float* Y      = (float*)ws;                                  // [8192][1024]

    // 1. cast x -> XM[:, :1024]
    cast_x_kernel<<<TM * TD / 4 / 256, 256, 0, stream>>>((const float4*)x, XM);

    // 2. weight transposes -> bf16, B^T layout
    transpose_to_bf16<<<dim3(512 / 32, 1024 / 32), 256, 0, stream>>>(w1, WbigT, 512, 0, 1024);
    transpose_to_bf16<<<dim3(512 / 32, 1024 / 32), 256, 0, stream>>>(w1 + (size_t)1024 * 512, WbigT, 512, 512, 1024);
    transpose_to_bf16<<<dim3(1024 / 32, 1024 / 32), 256, 0, stream>>>(wv_w, WbigT, 1024, 1024, 1024);
    transpose_to_bf16<<<dim3(1024 / 32, 2048 / 32), 256, 0, stream>>>(merge_w, MergeT, 1024, 0, 2048);

    // 3. GEMM1: UVV = X @ [w1_top | w1_bot | wv_w]   (M=8192, N=2048, K=1024)
    gemm_bt<<<dim3(2048 / 128, TM / 128), 256, 0, stream>>>(XM, 2048, WbigT, UVV, 2048, 1024);

    // 4. tau + msg -> XM[:, 1024:]
    taumsg_kernel<<<TM, 256, 0, stream>>>(UVV, b1, b2, w2, wv_b, XM);

    // 5. GEMM2: Y = [X | msg] @ merge_w   (M=8192, N=1024, K=2048)
    gemm_bt<<<dim3(1024 / 128, TM / 128), 256, 0, stream>>>(XM, 2048, MergeT, Y, 1024, 2048);

    // 6. LayerNorm -> out
    ln_kernel<<<TM, 256, 0, stream>>>(Y, merge_b, gamma, beta, out);
}

// Round 2
// 236.083 us; speedup vs baseline: 1.2048x; 1.2048x over previous
//
#include <hip/hip_runtime.h>
#include <hip/hip_bf16.h>

// Problem constants (B=2, T=4096, D=1024, H=512)
#define TT 4096
#define TD 1024
#define TH 512
#define TM 8192            // B*T tokens
#define EPS 1e-5f

typedef __bf16 bf16;
typedef __bf16 bf16x2 __attribute__((ext_vector_type(2)));
typedef __bf16 bf16x4 __attribute__((ext_vector_type(4)));
typedef __bf16 bf16x8 __attribute__((ext_vector_type(8)));
typedef float  f32x4  __attribute__((ext_vector_type(4)));

#define GLOBAL_AS __attribute__((address_space(1)))
#define LDS_AS    __attribute__((address_space(3)))

// ---------------------------------------------------------------------------
// Cast x (f32) into XM bf16 [8192][2048], columns 0..1023 (cols 1024.. are msg)
// ---------------------------------------------------------------------------
__global__ __launch_bounds__(256) void cast_x_kernel(const float4* __restrict__ x4,
                                                     bf16* __restrict__ XM) {
    int i = blockIdx.x * 256 + threadIdx.x;      // over 8192*1024/4 float4s
    float4 v = x4[i];
    int row = i >> 8;                            // 256 float4 per 1024-col row
    int c4  = i & 255;
    bf16x4 o;
    o[0] = (bf16)v.x; o[1] = (bf16)v.y; o[2] = (bf16)v.z; o[3] = (bf16)v.w;
    *(bf16x4*)(XM + (size_t)row * 2048 + c4 * 4) = o;
}

// ---------------------------------------------------------------------------
// Fused transpose of GEMM1 weights: w1_top | w1_bot | wv_w -> WbigT[2048 n][1024 k]
// grid (32, 32, 3), block 256 (32x8). z=0: w1 rows 0..1023 -> dstOff 0 (N=512)
// z=1: w1 rows 1024..2047 -> dstOff 512 (N=512); z=2: wv_w -> dstOff 1024 (N=1024)
// ---------------------------------------------------------------------------
__global__ __launch_bounds__(256) void transpose_w1wv(const float* __restrict__ w1,
                                                      const float* __restrict__ wv,
                                                      bf16* __restrict__ dst) {
    __shared__ float tile[32][33];
    const int z = blockIdx.z;
    const float* src; int N, dstOff;
    if (z == 0)      { src = w1;                      N = 512;  dstOff = 0;    }
    else if (z == 1) { src = w1 + (size_t)1024 * 512; N = 512;  dstOff = 512;  }
    else             { src = wv;                      N = 1024; dstOff = 1024; }
    int n0 = blockIdx.x * 32, k0 = blockIdx.y * 32;
    if (n0 >= N) return;
    int tx = threadIdx.x & 31, ty = threadIdx.x >> 5;
#pragma unroll
    for (int r = 0; r < 32; r += 8)
        tile[ty + r][tx] = src[(size_t)(k0 + ty + r) * N + n0 + tx];
    __syncthreads();
#pragma unroll
    for (int r = 0; r < 32; r += 8)
        dst[(size_t)(dstOff + n0 + ty + r) * 1024 + k0 + tx] = (bf16)tile[tx][ty + r];
}

// merge_w [2048][1024] -> MergeT[1024 n][2048 k], grid (32, 64)
__global__ __launch_bounds__(256) void transpose_merge(const float* __restrict__ src,
                                                       bf16* __restrict__ dst) {
    __shared__ float tile[32][33];
    int n0 = blockIdx.x * 32, k0 = blockIdx.y * 32;
    int tx = threadIdx.x & 31, ty = threadIdx.x >> 5;
#pragma unroll
    for (int r = 0; r < 32; r += 8)
        tile[ty + r][tx] = src[(size_t)(k0 + ty + r) * 1024 + n0 + tx];
    __syncthreads();
#pragma unroll
    for (int r = 0; r < 32; r += 8)
        dst[(size_t)(n0 + ty + r) * 2048 + k0 + tx] = (bf16)tile[tx][ty + r];
}

// ---------------------------------------------------------------------------
// bf16 GEMM (B-transposed): C[M][N] = A[M][K] @ BT[N][K]^T, OutT out.
// 128x128 tile, BK=64 (half the barrier drains of BK=32), 4 waves, 64x64/wave.
// LDS chunk-XOR swizzle: LDS chunk q of row r holds global chunk q^(r&7).
// (global_load_lds dst is lane-contiguous — swizzle lives in the SOURCE addr.)
// Keeps ds_read_b128 at the optimal 8 clk/wave (all 32 banks) at 128B row stride.
// ---------------------------------------------------------------------------
template <typename OutT>
__global__ __launch_bounds__(256) void gemm_bt(const bf16* __restrict__ A, int lda,
                                               const bf16* __restrict__ BT,
                                               OutT* __restrict__ C, int N, int K) {
    __shared__ bf16 As[128 * 64];
    __shared__ bf16 Bs[128 * 64];
    const int m0 = blockIdx.y * 128;
    const int n0 = blockIdx.x * 128;
    const int tid = threadIdx.x;
    const int wave = tid >> 6, lane = tid & 63;
    const int wr = (wave >> 1) * 64, wc = (wave & 1) * 64;
    const int lrow = lane & 15, cbase = lane >> 4;   // frag row, k-chunk
    const int sw = lrow & 7;                         // swizzle key (row&7 == lrow&7)

    f32x4 acc[4][4] = {};

    for (int k0 = 0; k0 < K; k0 += 64) {
        __syncthreads();   // previous compute done before overwrite
#pragma unroll
        for (int c = 0; c < 4; ++c) {
            int e = (c * 256 + tid) * 8;   // bf16 elem offset in 128x64 tile
            int row = e >> 6;
            int q = (e >> 3) & 7;          // LDS chunk within row
            int gcol = ((q ^ (row & 7)) << 3);
            const bf16* ga = A  + (size_t)(m0 + row) * lda + k0 + gcol;
            const bf16* gb = BT + (size_t)(n0 + row) * K   + k0 + gcol;
            __builtin_amdgcn_global_load_lds((const GLOBAL_AS void*)ga,
                                             (LDS_AS void*)(As + e), 16, 0, 0);
            __builtin_amdgcn_global_load_lds((const GLOBAL_AS void*)gb,
                                             (LDS_AS void*)(Bs + e), 16, 0, 0);
        }
        __syncthreads();   // drains vmcnt before use

#pragma unroll
        for (int kk = 0; kk < 2; ++kk) {
            const int qo = ((cbase + kk * 4) ^ sw) << 3;
            bf16x8 af[4], bfr[4];
#pragma unroll
            for (int i = 0; i < 4; ++i) {
                af[i]  = *(const bf16x8*)(As + (wr + i * 16 + lrow) * 64 + qo);
                bfr[i] = *(const bf16x8*)(Bs + (wc + i * 16 + lrow) * 64 + qo);
            }
#pragma unroll
            for (int i = 0; i < 4; ++i)
#pragma unroll
                for (int j = 0; j < 4; ++j)
                    acc[i][j] = __builtin_amdgcn_mfma_f32_16x16x32_bf16(af[i], bfr[j], acc[i][j], 0, 0, 0);
        }
    }

    // Epilogue: C/D layout col=lane&15, row=(lane>>4)*4+reg
    const int lr = (lane >> 4) * 4, lc = lane & 15;
#pragma unroll
    for (int i = 0; i < 4; ++i)
#pragma unroll
        for (int j = 0; j < 4; ++j)
#pragma unroll
            for (int r = 0; r < 4; ++r)
                C[(size_t)(m0 + wr + i * 16 + lr + r) * N + (n0 + wc + j * 16 + lc)]
                    = (OutT)acc[i][j][r];
}

// ---------------------------------------------------------------------------
// tau + msg: per token (block), UVV = [U(512) | Vn(512) | V(1024)] bf16 per row.
// msg[t] = sum_w tau[t,w] * V[t-w-1] (valid) + (sum_w tau) * wv_b
// writes msg as bf16 into XM cols 1024..2047
// ---------------------------------------------------------------------------
__global__ __launch_bounds__(256) void taumsg_kernel(const bf16* __restrict__ UVV,
                                                     const float* __restrict__ b1,
                                                     const float* __restrict__ b2,
                                                     const float* __restrict__ w2,
                                                     const float* __restrict__ wv_b,
                                                     bf16* __restrict__ XM) {
    const int row = blockIdx.x;          // token 0..8191
    const int t = row & (TT - 1);
    const int tid = threadIdx.x;

    // phase 1: tau_w. Each thread owns h = 2*tid, 2*tid+1.
    const int h = tid * 2;
    bf16x2 ub = *(const bf16x2*)(UVV + (size_t)row * 2048 + h);
    float u0 = (float)ub[0] + b1[h];
    float u1 = (float)ub[1] + b1[h + 1];
    const float w20 = w2[h], w21 = w2[h + 1];

    float partial[4];
#pragma unroll
    for (int w = 0; w < 4; ++w) {
        float vn0 = 0.f, vn1 = 0.f;
        if (t >= w + 1) {
            bf16x2 vb = *(const bf16x2*)(UVV + (size_t)(row - w - 1) * 2048 + 512 + h);
            vn0 = (float)vb[0]; vn1 = (float)vb[1];
        }
        float z0 = u0 + vn0, z1 = u1 + vn1;
        float h0 = z0 / (1.f + __expf(-z0));
        float h1 = z1 / (1.f + __expf(-z1));
        partial[w] = h0 * w20 + h1 * w21;
    }
#pragma unroll
    for (int w = 0; w < 4; ++w)
        for (int off = 32; off; off >>= 1)
            partial[w] += __shfl_down(partial[w], off, 64);

    __shared__ float red[4][4];
    __shared__ float staus[4];
    const int lane = tid & 63, wave = tid >> 6;
    if (lane == 0)
#pragma unroll
        for (int w = 0; w < 4; ++w) red[w][wave] = partial[w];
    __syncthreads();
    if (tid < 4) {
        float s = red[tid][0] + red[tid][1] + red[tid][2] + red[tid][3] + b2[0];
        staus[tid] = 1.f / (1.f + __expf(-s));
    }
    __syncthreads();
    const float tau0 = staus[0], tau1 = staus[1], tau2 = staus[2], tau3 = staus[3];
    const float tsum = tau0 + tau1 + tau2 + tau3;

    // phase 2: msg. Each thread owns 4 consecutive d.
    const int d0 = tid * 4;
    float4 wb = *(const float4*)(wv_b + d0);
    float m[4] = {tsum * wb.x, tsum * wb.y, tsum * wb.z, tsum * wb.w};
    const float taus[4] = {tau0, tau1, tau2, tau3};
#pragma unroll
    for (int w = 0; w < 4; ++w) {
        if (t >= w + 1) {
            bf16x4 v = *(const bf16x4*)(UVV + (size_t)(row - w - 1) * 2048 + 1024 + d0);
#pragma unroll
            for (int j = 0; j < 4; ++j) m[j] += taus[w] * (float)v[j];
        }
    }
    bf16x4 o;
#pragma unroll
    for (int j = 0; j < 4; ++j) o[j] = (bf16)m[j];
    *(bf16x4*)(XM + (size_t)row * 2048 + 1024 + d0) = o;
}

// ---------------------------------------------------------------------------
// LayerNorm over D=1024 on bf16 Y: out = (y+merge_b - mu)*rsqrt(var+eps)*gamma+beta
// ---------------------------------------------------------------------------
__global__ __launch_bounds__(256) void ln_kernel(const bf16* __restrict__ Y,
                                                 const float* __restrict__ merge_b,
                                                 const float* __restrict__ gamma,
                                                 const float* __restrict__ beta,
                                                 float* __restrict__ out) {
    const int row = blockIdx.x;
    const int tid = threadIdx.x;
    const int d0 = tid * 4;
    bf16x4 y4 = *(const bf16x4*)(Y + (size_t)row * TD + d0);
    float4 mb = *(const float4*)(merge_b + d0);
    float v[4] = {(float)y4[0] + mb.x, (float)y4[1] + mb.y,
                  (float)y4[2] + mb.z, (float)y4[3] + mb.w};
    float s = v[0] + v[1] + v[2] + v[3];
    float ss = v[0]*v[0] + v[1]*v[1] + v[2]*v[2] + v[3]*v[3];
    for (int off = 32; off; off >>= 1) {
        s  += __shfl_down(s, off, 64);
        ss += __shfl_down(ss, off, 64);
    }
    __shared__ float rs[4], rss[4];
    __shared__ float smu, srstd;
    const int lane = tid & 63, wave = tid >> 6;
    if (lane == 0) { rs[wave] = s; rss[wave] = ss; }
    __syncthreads();
    if (tid == 0) {
        float S = rs[0] + rs[1] + rs[2] + rs[3];
        float SS = rss[0] + rss[1] + rss[2] + rss[3];
        float mu = S * (1.f / TD);
        float var = SS * (1.f / TD) - mu * mu;
        smu = mu; srstd = rsqrtf(var + EPS);
    }
    __syncthreads();
    const float mu = smu, r = srstd;
    float4 g = *(const float4*)(gamma + d0);
    float4 bt = *(const float4*)(beta + d0);
    float4 o;
    o.x = (v[0] - mu) * r * g.x + bt.x;
    o.y = (v[1] - mu) * r * g.y + bt.y;
    o.z = (v[2] - mu) * r * g.z + bt.z;
    o.w = (v[3] - mu) * r * g.w + bt.w;
    *(float4*)(out + (size_t)row * TD + d0) = o;
}

// ---------------------------------------------------------------------------
extern "C" void kernel_launch(void* const* d_in, const int* in_sizes, int n_in,
                              void* d_out, int out_size, void* d_ws, size_t ws_size,
                              hipStream_t stream) {
    const float* x       = (const float*)d_in[0];
    const float* w1      = (const float*)d_in[1];
    const float* b1      = (const float*)d_in[2];
    const float* w2      = (const float*)d_in[3];
    const float* b2      = (const float*)d_in[4];
    const float* wv_w    = (const float*)d_in[5];
    const float* wv_b    = (const float*)d_in[6];
    const float* merge_w = (const float*)d_in[7];
    const float* merge_b = (const float*)d_in[8];
    const float* gamma   = (const float*)d_in[9];
    const float* beta    = (const float*)d_in[10];
    float* out = (float*)d_out;

    char* ws = (char*)d_ws;
    bf16*  XM     = (bf16*)ws;   ws += (size_t)TM * 2048 * 2;   // [8192][2048] = X | msg
    bf16*  WbigT  = (bf16*)ws;   ws += (size_t)2048 * 1024 * 2; // [2048 n][1024 k]
    bf16*  MergeT = (bf16*)ws;   ws += (size_t)1024 * 2048 * 2; // [1024 n][2048 k]
    bf16*  UVV    = (bf16*)ws;   ws += (size_t)TM * 2048 * 2;   // [8192][U|Vn|V] bf16
    bf16*  Y      = (bf16*)ws;                                  // [8192][1024] bf16

    // 1. cast x -> XM[:, :1024]
    cast_x_kernel<<<TM * TD / 4 / 256, 256, 0, stream>>>((const float4*)x, XM);

    // 2. weight transposes -> bf16, B^T layout (w1 halves + wv fused in one launch)
    transpose_w1wv<<<dim3(32, 32, 3), 256, 0, stream>>>(w1, wv_w, WbigT);
    transpose_merge<<<dim3(32, 64), 256, 0, stream>>>(merge_w, MergeT);

    // 3. GEMM1: UVV = X @ [w1_top | w1_bot | wv_w]   (M=8192, N=2048, K=1024)
    gemm_bt<bf16><<<dim3(2048 / 128, TM / 128), 256, 0, stream>>>(XM, 2048, WbigT, UVV, 2048, 1024);

    // 4. tau + msg -> XM[:, 1024:]
    taumsg_kernel<<<TM, 256, 0, stream>>>(UVV, b1, b2, w2, wv_b, XM);

    // 5. GEMM2: Y = [X | msg] @ merge_w   (M=8192, N=1024, K=2048)
    gemm_bt<bf16><<<dim3(1024 / 128, TM / 128), 256, 0, stream>>>(XM, 2048, MergeT, Y, 1024, 2048);

    // 6. LayerNorm -> out
    ln_kernel<<<TM, 256, 0, stream>>>(Y, merge_b, gamma, beta, out);
}